// Round 15
// baseline (357.957 us; speedup 1.0000x reference)
//
#include <hip/hip_runtime.h>

#define NBINS        2048     // float bits >> 20 : 8 exp + 3 mantissa bits
#define THREADS      256
#define SCAN_BLOCKS  2304     // n4 = 4,718,592 = 8 * SCAN_BLOCKS*THREADS exactly
#define HIST_BLOCKS  512
#define CNTSH        44       // count lives in bits [44,64) of packed u64
#define SAMPLE_SHIFT 3        // 1/8 grouped subsample (first 256 f4 of each 2048)
#define GROUPF4      2048
#define SSTRIDE      (SCAN_BLOCKS * THREADS)   // scan grid stride in float4

// ---- forced-pipeline primitives (immune to compiler flattening) ----
#define GLOAD(dst, ptr) \
    asm volatile("global_load_dwordx4 %0, %1, off" : "=v"(dst) : "v"(ptr))
#define VMWAIT(N) do { asm volatile("s_waitcnt vmcnt(" #N ")" ::: "memory"); \
                       __builtin_amdgcn_sched_barrier(0); } while (0)

__device__ __forceinline__ float bce_loss(float g, float p) {
    // torch-style BCE with log clamp at -100:
    // loss = g*min(-log p,100) + (1-g)*min(-log(1-p),100)
    float nlp = fminf(-__logf(p), 100.0f);
    float nlq = fminf(-__logf(1.0f - p), 100.0f);
    return fmaf(g, nlp - nlq, nlq);
}

__device__ __forceinline__ void scan_elem(float g, float p,
    unsigned int& posc, unsigned int& ignc, float& ps)
{
    bool isPos = (g >= 0.9f);
    bool isIgn = (g >= 0.8f) && !isPos;
    posc += isPos;
    ignc += isIgn;
    float loss = bce_loss(g, p);
    ps += isPos ? loss : 0.0f;
}

__device__ __forceinline__ void scan4(float4 g, float4 p,
    unsigned int& posc, unsigned int& ignc, float& ps)
{
    scan_elem(g.x, p.x, posc, ignc, ps);
    scan_elem(g.y, p.y, posc, ignc, ps);
    scan_elem(g.z, p.z, posc, ignc, ps);
    scan_elem(g.w, p.w, posc, ignc, ps);
}

#define ISSUE(s, k) do {                               \
    GLOAD(g##s, g4p + i0 + (k) * SSTRIDE);             \
    GLOAD(p##s, p4p + i0 + (k) * SSTRIDE);             \
} while (0)

#define PROCS(s) scan4(g##s, p##s, posc, ignc, ps)

// ---------------- kernel 1: pure streaming scan (NO LDS) ----------------
// __launch_bounds__(256, 4): pin VGPR budget at 512/4 = 128 so the 8-slot
// (64 data VGPR) asm pipeline stays in registers (R13/R14: lean budgets
// spilled it to scratch -> 340 us).
__global__ __launch_bounds__(THREADS, 4) void scan_kernel(
    const float* __restrict__ gt, const float* __restrict__ pred,
    unsigned int* __restrict__ posIgn, double* __restrict__ psum,
    int n4, int nTail, long long tailBase)
{
    const float4* g4p = (const float4*)gt;
    const float4* p4p = (const float4*)pred;

    unsigned int posc = 0, ignc = 0;
    float ps = 0.0f;
    const int i0 = blockIdx.x * THREADS + threadIdx.x;

    if (n4 == 8 * SSTRIDE && gridDim.x == SCAN_BLOCKS) {
        // fully-unrolled 8-iteration pipeline: 16 loads in flight, counted drain
        float4 gA, pA, gB, pB, gC, pC, gD, pD;
        float4 gE, pE, gF, pF, gG, pG, gH, pH;
        ISSUE(A, 0); ISSUE(B, 1); ISSUE(C, 2); ISSUE(D, 3);
        ISSUE(E, 4); ISSUE(F, 5); ISSUE(G, 6); ISSUE(H, 7);
        VMWAIT(14); PROCS(A);
        VMWAIT(12); PROCS(B);
        VMWAIT(10); PROCS(C);
        VMWAIT(8);  PROCS(D);
        VMWAIT(6);  PROCS(E);
        VMWAIT(4);  PROCS(F);
        VMWAIT(2);  PROCS(G);
        VMWAIT(0);  PROCS(H);
    } else {
        for (int i = i0; i < n4; i += gridDim.x * blockDim.x) {
            float4 g4 = g4p[i];
            float4 p4 = p4p[i];
            scan4(g4, p4, posc, ignc, ps);
        }
    }
    if (blockIdx.x == 0 && threadIdx.x < nTail) {
        long long e = tailBase + threadIdx.x;
        scan_elem(gt[e], pred[e], posc, ignc, ps);
    }

    // wave-64 reduce, one atomic per wave
    double pd = (double)ps;
    for (int off = 32; off > 0; off >>= 1) {
        posc += __shfl_down(posc, off);
        ignc += __shfl_down(ignc, off);
        pd   += __shfl_down(pd, off);
    }
    if ((threadIdx.x & 63) == 0) {
        if (posc) atomicAdd(&posIgn[0], posc);
        if (ignc) atomicAdd(&posIgn[1], ignc);
        atomicAdd(psum, pd);
    }
}

// ---------------- kernel 2: grouped 1/8-sample histogram ----------------
__global__ __launch_bounds__(THREADS) void hist_kernel(
    const float* __restrict__ gt, const float* __restrict__ pred,
    unsigned int* __restrict__ counts, unsigned long long* __restrict__ sums,
    int n4)
{
    __shared__ unsigned long long hist[NBINS];
    for (int j = threadIdx.x; j < NBINS; j += THREADS) hist[j] = 0ull;
    __syncthreads();

    const float4* g4p = (const float4*)gt;
    const float4* p4p = (const float4*)pred;

    const int nGroups = (n4 + GROUPF4 - 1) / GROUPF4;
    for (int c = blockIdx.x; c < nGroups; c += gridDim.x) {
        int idx = c * GROUPF4 + threadIdx.x;        // coalesced 4 KB chunk
        if (idx < n4) {
            float4 g = g4p[idx];
            float4 p = p4p[idx];
            #pragma unroll
            for (int e = 0; e < 4; ++e) {
                float ge = (e == 0) ? g.x : (e == 1) ? g.y : (e == 2) ? g.z : g.w;
                float pe = (e == 0) ? p.x : (e == 1) ? p.y : (e == 2) ? p.z : p.w;
                if (ge < 0.8f) {
                    float loss = bce_loss(ge, pe);
                    unsigned int b = 0;
                    if (loss > 0.0f) {             // guard loss==0 / -0.0
                        b = __float_as_uint(loss) >> 20;
                        if (b > NBINS - 1) b = NBINS - 1;
                    }
                    unsigned long long q =
                        (unsigned long long)(unsigned int)(fmaf(loss, 1048576.0f, 0.5f));
                    atomicAdd(&hist[b], (1ull << CNTSH) | q);
                }
            }
        }
    }

    __syncthreads();
    // flush sparse per-block histogram: 1 u32 + 1 u64 atomic per hot bin
    for (int b = threadIdx.x; b < NBINS; b += THREADS) {
        unsigned long long v = hist[b];
        if (v) {
            atomicAdd(&counts[b], (unsigned int)(v >> CNTSH));
            atomicAdd(&sums[b],   v & ((1ull << CNTSH) - 1));
        }
    }
}

__global__ __launch_bounds__(256) void finalize(
    const unsigned int* __restrict__ counts,
    const unsigned long long* __restrict__ sums,
    const unsigned int* __restrict__ posIgn, const double* __restrict__ psum,
    float* __restrict__ out, long long nTotal)
{
    __shared__ unsigned long long scnt[256];
    __shared__ double             ssum[256];
    __shared__ int                s_chunk;
    __shared__ double             s_topk;
    __shared__ double             s_allsum;

    const int t = threadIdx.x;
    const int BPT = NBINS / 256;          // 8 bins per thread
    const int base = t * BPT;
    const double INVFIX = 1.0 / 1048576.0;
    const double SCALE = (double)(1 << SAMPLE_SHIFT);   // 8.0

    unsigned long long c = 0; double s = 0.0;
    #pragma unroll
    for (int i = 0; i < BPT; ++i) {
        c += counts[base + i];
        s += (double)sums[base + i] * INVFIX;
    }
    scnt[t] = c; ssum[t] = s;
    if (t == 0) { s_chunk = -1; s_topk = 0.0; }
    __syncthreads();

    // inclusive suffix scan over 256 chunks (sample counts / sums)
    for (int off = 1; off < 256; off <<= 1) {
        unsigned long long cv = (t + off < 256) ? scnt[t + off] : 0ull;
        double             sv = (t + off < 256) ? ssum[t + off] : 0.0;
        __syncthreads();
        scnt[t] += cv; ssum[t] += sv;
        __syncthreads();
    }
    if (t == 0) s_allsum = ssum[0];
    __syncthreads();

    const unsigned int pos = posIgn[0];
    const unsigned int ign = posIgn[1];
    const unsigned long long neg =
        (unsigned long long)nTotal - pos - ign;        // EXACT negative count

    // k = floor(min(max(pos,1)*3.0, neg)) in f32, mirroring reference
    float kf = fminf(fmaxf((float)pos, 1.0f) * 3.0f, (float)neg);
    long long k = (long long)floorf(kf);
    unsigned long long ku = (unsigned long long)(k > 0 ? k : 0);

    unsigned long long Sincl = scnt[t];
    unsigned long long Sexcl = (t < 255) ? scnt[t + 1] : 0ull;
    double SexclSum          = (t < 255) ? ssum[t + 1] : 0.0;

    // compare in scaled (x8) space
    if (ku > 0 && (Sexcl << SAMPLE_SHIFT) < ku && (Sincl << SAMPLE_SHIFT) >= ku) {
        double topk = SCALE * SexclSum;
        double need = (double)ku - SCALE * (double)Sexcl;   // scaled rank deficit
        for (int i = BPT - 1; i >= 0 && need > 0.0; --i) {
            int b = base + i;
            unsigned long long cb = counts[b];
            if (!cb) continue;
            double sb = (double)sums[b] * INVFIX;           // sample sum in bin
            double nb = SCALE * (double)cb;                 // scaled bin count
            if (nb <= need) {
                topk += SCALE * sb;
                need -= nb;
            } else {
                // partial bin: uniform-within-bin model anchored at bin mean
                float lo = __uint_as_float((unsigned)b << 20);
                float hi = (b + 1 < NBINS) ? __uint_as_float((unsigned)(b + 1) << 20) : lo;
                double w = (double)hi - (double)lo;
                double mean = sb / (double)cb;
                topk += need * (mean + 0.5 * w * (1.0 - need / nb));
                need = 0.0;
            }
        }
        s_topk = topk;
        s_chunk = t;
    }
    __syncthreads();

    if (t == 0) {
        double topk;
        if (s_chunk >= 0)      topk = s_topk;
        else if (ku > 0)       topk = SCALE * s_allsum;  // k beyond scaled total
        else                   topk = 0.0;
        float denf = (float)pos + (float)k;
        denf += 1e-4f;
        double res = (3.0 * (*psum) + topk) / (double)denf;
        out[0] = (float)res;
    }
}

extern "C" void kernel_launch(void* const* d_in, const int* in_sizes, int n_in,
                              void* d_out, int out_size, void* d_ws, size_t ws_size,
                              hipStream_t stream) {
    const float* gt   = (const float*)d_in[0];
    const float* pred = (const float*)d_in[1];
    float* out = (float*)d_out;

    // ws: [0,8) f64 psum | [8,12) u32 pos | [12,16) u32 ign
    //     | [16, 16+NBINS*4) u32 counts | then NBINS*8 u64 sums
    double*             psum   = (double*)d_ws;
    unsigned int*       posIgn = (unsigned int*)((char*)d_ws + 8);
    unsigned int*       counts = (unsigned int*)((char*)d_ws + 16);
    unsigned long long* sums   = (unsigned long long*)((char*)d_ws + 16 + NBINS * sizeof(unsigned int));

    size_t zbytes = 16 + (size_t)NBINS * (sizeof(unsigned int) + sizeof(unsigned long long));
    hipMemsetAsync(d_ws, 0, zbytes, stream);

    long long n = (long long)in_sizes[0];
    int n4 = (int)(n >> 2);
    int nTail = (int)(n & 3);
    long long tailBase = (long long)n4 * 4;

    scan_kernel<<<dim3(SCAN_BLOCKS), dim3(THREADS), 0, stream>>>(
        gt, pred, posIgn, psum, n4, nTail, tailBase);
    hist_kernel<<<dim3(HIST_BLOCKS), dim3(THREADS), 0, stream>>>(
        gt, pred, counts, sums, n4);
    finalize<<<dim3(1), dim3(256), 0, stream>>>(counts, sums, posIgn, psum, out, n);
}

// Round 16
// 328.680 us; speedup vs baseline: 1.0891x; 1.0891x over previous
//
#include <hip/hip_runtime.h>

#define NBINS        2048     // float bits >> 20 : 8 exp + 3 mantissa bits
#define THREADS      256
#define SCAN_BLOCKS  2048     // n4 = 4,718,592 = 9 * SCAN_BLOCKS*THREADS exactly
#define HIST_BLOCKS  512
#define CNTSH        44       // count lives in bits [44,64) of packed u64
#define SAMPLE_SHIFT 3        // 1/8 grouped subsample (first 256 f4 of each 2048)
#define GROUPF4      2048
#define SSTRIDE      (SCAN_BLOCKS * THREADS)   // 524288 float4 per grid step

#define VMWAIT(N) do { asm volatile("s_waitcnt vmcnt(" #N ")" ::: "memory"); \
                       __builtin_amdgcn_sched_barrier(0); } while (0)

__device__ __forceinline__ float bce_loss(float g, float p) {
    // torch-style BCE with log clamp at -100:
    // loss = g*min(-log p,100) + (1-g)*min(-log(1-p),100)
    float nlp = fminf(-__logf(p), 100.0f);
    float nlq = fminf(-__logf(1.0f - p), 100.0f);
    return fmaf(g, nlp - nlq, nlq);
}

__device__ __forceinline__ void scan_elem(float g, float p,
    unsigned int& posc, unsigned int& ignc, float& ps)
{
    bool isPos = (g >= 0.9f);
    bool isIgn = (g >= 0.8f) && !isPos;
    posc += isPos;
    ignc += isIgn;
    float loss = bce_loss(g, p);
    ps += isPos ? loss : 0.0f;
}

__device__ __forceinline__ void scan4(float4 g, float4 p,
    unsigned int& posc, unsigned int& ignc, float& ps)
{
    scan_elem(g.x, p.x, posc, ignc, ps);
    scan_elem(g.y, p.y, posc, ignc, ps);
    scan_elem(g.z, p.z, posc, ignc, ps);
    scan_elem(g.w, p.w, posc, ignc, ps);
}

// ---------------- kernel 1: streaming scan via global_load_lds ----------------
// Data is DMA'd global->LDS (zero VGPR cost for in-flight loads -> nothing for
// the register allocator to spill; R4-R15 lesson: VGPR-buffered pipelines spill).
// Each wave reads only the 1KB slot its own gload_lds wrote -> no barriers.
__global__ __launch_bounds__(THREADS) void scan_kernel(
    const float* __restrict__ gt, const float* __restrict__ pred,
    unsigned int* __restrict__ posIgn, double* __restrict__ psum,
    int n4, int nTail, long long tailBase)
{
    __shared__ float4 sgA[THREADS], spA[THREADS];   // buffer A (4KB + 4KB)
    __shared__ float4 sgB[THREADS], spB[THREADS];   // buffer B (4KB + 4KB)

    const float4* g4p = (const float4*)gt;
    const float4* p4p = (const float4*)pred;

    unsigned int posc = 0, ignc = 0;
    float ps = 0.0f;
    const int tid = threadIdx.x;
    const int wbase = tid & ~63;                    // wave-uniform LDS slot base
    const int i0 = blockIdx.x * THREADS + tid;

#define LOADT(BUF, T) do {                                                    \
    __builtin_amdgcn_global_load_lds(g4p + i0 + (T) * SSTRIDE,                \
                                     &sg##BUF[wbase], 16, 0, 0);              \
    __builtin_amdgcn_global_load_lds(p4p + i0 + (T) * SSTRIDE,                \
                                     &sp##BUF[wbase], 16, 0, 0);              \
} while (0)

#define CONS(BUF) do {                                                        \
    float4 g_ = sg##BUF[tid];                                                 \
    float4 p_ = sp##BUF[tid];                                                 \
    scan4(g_, p_, posc, ignc, ps);                                            \
} while (0)

    if (n4 == 9 * SSTRIDE && gridDim.x == SCAN_BLOCKS) {
        LOADT(A, 0); LOADT(B, 1);
        VMWAIT(2); { float4 g_=sgA[tid], p_=spA[tid]; LOADT(A, 2); scan4(g_,p_,posc,ignc,ps); }  // t0
        VMWAIT(2); { float4 g_=sgB[tid], p_=spB[tid]; LOADT(B, 3); scan4(g_,p_,posc,ignc,ps); }  // t1
        VMWAIT(2); { float4 g_=sgA[tid], p_=spA[tid]; LOADT(A, 4); scan4(g_,p_,posc,ignc,ps); }  // t2
        VMWAIT(2); { float4 g_=sgB[tid], p_=spB[tid]; LOADT(B, 5); scan4(g_,p_,posc,ignc,ps); }  // t3
        VMWAIT(2); { float4 g_=sgA[tid], p_=spA[tid]; LOADT(A, 6); scan4(g_,p_,posc,ignc,ps); }  // t4
        VMWAIT(2); { float4 g_=sgB[tid], p_=spB[tid]; LOADT(B, 7); scan4(g_,p_,posc,ignc,ps); }  // t5
        VMWAIT(2); { float4 g_=sgA[tid], p_=spA[tid]; LOADT(A, 8); scan4(g_,p_,posc,ignc,ps); }  // t6
        VMWAIT(2); CONS(B);                                                                       // t7
        VMWAIT(0); CONS(A);                                                                       // t8
    } else {
        for (int i = i0; i < n4; i += gridDim.x * blockDim.x) {
            float4 g4 = g4p[i];
            float4 p4 = p4p[i];
            scan4(g4, p4, posc, ignc, ps);
        }
    }
    if (blockIdx.x == 0 && threadIdx.x < nTail) {
        long long e = tailBase + threadIdx.x;
        scan_elem(gt[e], pred[e], posc, ignc, ps);
    }

    // wave-64 reduce, one atomic per wave
    double pd = (double)ps;
    for (int off = 32; off > 0; off >>= 1) {
        posc += __shfl_down(posc, off);
        ignc += __shfl_down(ignc, off);
        pd   += __shfl_down(pd, off);
    }
    if ((threadIdx.x & 63) == 0) {
        if (posc) atomicAdd(&posIgn[0], posc);
        if (ignc) atomicAdd(&posIgn[1], ignc);
        atomicAdd(psum, pd);
    }
#undef LOADT
#undef CONS
}

// ---------------- kernel 2: grouped 1/8-sample histogram ----------------
__global__ __launch_bounds__(THREADS) void hist_kernel(
    const float* __restrict__ gt, const float* __restrict__ pred,
    unsigned int* __restrict__ counts, unsigned long long* __restrict__ sums,
    int n4)
{
    __shared__ unsigned long long hist[NBINS];
    for (int j = threadIdx.x; j < NBINS; j += THREADS) hist[j] = 0ull;
    __syncthreads();

    const float4* g4p = (const float4*)gt;
    const float4* p4p = (const float4*)pred;

    const int nGroups = (n4 + GROUPF4 - 1) / GROUPF4;
    for (int c = blockIdx.x; c < nGroups; c += gridDim.x) {
        int idx = c * GROUPF4 + threadIdx.x;        // coalesced 4 KB chunk
        if (idx < n4) {
            float4 g = g4p[idx];
            float4 p = p4p[idx];
            #pragma unroll
            for (int e = 0; e < 4; ++e) {
                float ge = (e == 0) ? g.x : (e == 1) ? g.y : (e == 2) ? g.z : g.w;
                float pe = (e == 0) ? p.x : (e == 1) ? p.y : (e == 2) ? p.z : p.w;
                if (ge < 0.8f) {
                    float loss = bce_loss(ge, pe);
                    unsigned int b = 0;
                    if (loss > 0.0f) {             // guard loss==0 / -0.0
                        b = __float_as_uint(loss) >> 20;
                        if (b > NBINS - 1) b = NBINS - 1;
                    }
                    unsigned long long q =
                        (unsigned long long)(unsigned int)(fmaf(loss, 1048576.0f, 0.5f));
                    atomicAdd(&hist[b], (1ull << CNTSH) | q);
                }
            }
        }
    }

    __syncthreads();
    // flush sparse per-block histogram: 1 u32 + 1 u64 atomic per hot bin
    for (int b = threadIdx.x; b < NBINS; b += THREADS) {
        unsigned long long v = hist[b];
        if (v) {
            atomicAdd(&counts[b], (unsigned int)(v >> CNTSH));
            atomicAdd(&sums[b],   v & ((1ull << CNTSH) - 1));
        }
    }
}

__global__ __launch_bounds__(256) void finalize(
    const unsigned int* __restrict__ counts,
    const unsigned long long* __restrict__ sums,
    const unsigned int* __restrict__ posIgn, const double* __restrict__ psum,
    float* __restrict__ out, long long nTotal)
{
    __shared__ unsigned long long scnt[256];
    __shared__ double             ssum[256];
    __shared__ int                s_chunk;
    __shared__ double             s_topk;
    __shared__ double             s_allsum;

    const int t = threadIdx.x;
    const int BPT = NBINS / 256;          // 8 bins per thread
    const int base = t * BPT;
    const double INVFIX = 1.0 / 1048576.0;
    const double SCALE = (double)(1 << SAMPLE_SHIFT);   // 8.0

    unsigned long long c = 0; double s = 0.0;
    #pragma unroll
    for (int i = 0; i < BPT; ++i) {
        c += counts[base + i];
        s += (double)sums[base + i] * INVFIX;
    }
    scnt[t] = c; ssum[t] = s;
    if (t == 0) { s_chunk = -1; s_topk = 0.0; }
    __syncthreads();

    // inclusive suffix scan over 256 chunks (sample counts / sums)
    for (int off = 1; off < 256; off <<= 1) {
        unsigned long long cv = (t + off < 256) ? scnt[t + off] : 0ull;
        double             sv = (t + off < 256) ? ssum[t + off] : 0.0;
        __syncthreads();
        scnt[t] += cv; ssum[t] += sv;
        __syncthreads();
    }
    if (t == 0) s_allsum = ssum[0];
    __syncthreads();

    const unsigned int pos = posIgn[0];
    const unsigned int ign = posIgn[1];
    const unsigned long long neg =
        (unsigned long long)nTotal - pos - ign;        // EXACT negative count

    // k = floor(min(max(pos,1)*3.0, neg)) in f32, mirroring reference
    float kf = fminf(fmaxf((float)pos, 1.0f) * 3.0f, (float)neg);
    long long k = (long long)floorf(kf);
    unsigned long long ku = (unsigned long long)(k > 0 ? k : 0);

    unsigned long long Sincl = scnt[t];
    unsigned long long Sexcl = (t < 255) ? scnt[t + 1] : 0ull;
    double SexclSum          = (t < 255) ? ssum[t + 1] : 0.0;

    // compare in scaled (x8) space
    if (ku > 0 && (Sexcl << SAMPLE_SHIFT) < ku && (Sincl << SAMPLE_SHIFT) >= ku) {
        double topk = SCALE * SexclSum;
        double need = (double)ku - SCALE * (double)Sexcl;   // scaled rank deficit
        for (int i = BPT - 1; i >= 0 && need > 0.0; --i) {
            int b = base + i;
            unsigned long long cb = counts[b];
            if (!cb) continue;
            double sb = (double)sums[b] * INVFIX;           // sample sum in bin
            double nb = SCALE * (double)cb;                 // scaled bin count
            if (nb <= need) {
                topk += SCALE * sb;
                need -= nb;
            } else {
                // partial bin: uniform-within-bin model anchored at bin mean
                float lo = __uint_as_float((unsigned)b << 20);
                float hi = (b + 1 < NBINS) ? __uint_as_float((unsigned)(b + 1) << 20) : lo;
                double w = (double)hi - (double)lo;
                double mean = sb / (double)cb;
                topk += need * (mean + 0.5 * w * (1.0 - need / nb));
                need = 0.0;
            }
        }
        s_topk = topk;
        s_chunk = t;
    }
    __syncthreads();

    if (t == 0) {
        double topk;
        if (s_chunk >= 0)      topk = s_topk;
        else if (ku > 0)       topk = SCALE * s_allsum;  // k beyond scaled total
        else                   topk = 0.0;
        float denf = (float)pos + (float)k;
        denf += 1e-4f;
        double res = (3.0 * (*psum) + topk) / (double)denf;
        out[0] = (float)res;
    }
}

extern "C" void kernel_launch(void* const* d_in, const int* in_sizes, int n_in,
                              void* d_out, int out_size, void* d_ws, size_t ws_size,
                              hipStream_t stream) {
    const float* gt   = (const float*)d_in[0];
    const float* pred = (const float*)d_in[1];
    float* out = (float*)d_out;

    // ws: [0,8) f64 psum | [8,12) u32 pos | [12,16) u32 ign
    //     | [16, 16+NBINS*4) u32 counts | then NBINS*8 u64 sums
    double*             psum   = (double*)d_ws;
    unsigned int*       posIgn = (unsigned int*)((char*)d_ws + 8);
    unsigned int*       counts = (unsigned int*)((char*)d_ws + 16);
    unsigned long long* sums   = (unsigned long long*)((char*)d_ws + 16 + NBINS * sizeof(unsigned int));

    size_t zbytes = 16 + (size_t)NBINS * (sizeof(unsigned int) + sizeof(unsigned long long));
    hipMemsetAsync(d_ws, 0, zbytes, stream);

    long long n = (long long)in_sizes[0];
    int n4 = (int)(n >> 2);
    int nTail = (int)(n & 3);
    long long tailBase = (long long)n4 * 4;

    scan_kernel<<<dim3(SCAN_BLOCKS), dim3(THREADS), 0, stream>>>(
        gt, pred, posIgn, psum, n4, nTail, tailBase);
    hist_kernel<<<dim3(HIST_BLOCKS), dim3(THREADS), 0, stream>>>(
        gt, pred, counts, sums, n4);
    finalize<<<dim3(1), dim3(256), 0, stream>>>(counts, sums, posIgn, psum, out, n);
}

// Round 17
// 87.142 us; speedup vs baseline: 4.1077x; 3.7718x over previous
//
#include <hip/hip_runtime.h>

#define NBINS    2048          // float bits >> 20 : 8 exp + 3 mantissa bits
#define REPL     4             // per-lane-group replicas (R2-proven codegen shape)
#define THREADS  256
#define BLOCKS   512           // 2 blocks/CU, 64 KB LDS -> fat-codegen regime
#define CNTSH    44            // count lives in bits [44,64)

__device__ __forceinline__ void process_elem(
    float g, float p,
    unsigned int& posc, float& ps,
    unsigned long long* hist, unsigned int repl)
{
    // torch-style BCE with log clamp at -100:
    // loss = g*min(-log p,100) + (1-g)*min(-log(1-p),100)
    float nlp = fminf(-__logf(p), 100.0f);
    float nlq = fminf(-__logf(1.0f - p), 100.0f);
    float loss = fmaf(g, nlp - nlq, nlq);     // g*nlp + (1-g)*nlq

    bool isPos = (g >= 0.9f);
    bool isNeg = (g < 0.8f);
    posc += isPos;
    if (isPos) ps += loss;
    if (isNeg) {
        unsigned int b = 0;
        if (loss > 0.0f) {                     // guard -0.0 / nonpositive
            b = __float_as_uint(loss) >> 20;
            if (b > NBINS - 1) b = NBINS - 1;
        }
        // fixed-point quantize (loss <= 100 -> fits u32); pack count|sum
        unsigned long long q =
            (unsigned long long)(unsigned int)(fmaf(loss, 1048576.0f, 0.5f));
        atomicAdd(&hist[(b << 2) | repl], (1ull << CNTSH) | q);
    }
}

__device__ __forceinline__ void process4(
    float4 g, float4 p,
    unsigned int& posc, float& ps,
    unsigned long long* hist, unsigned int repl)
{
    process_elem(g.x, p.x, posc, ps, hist, repl);
    process_elem(g.y, p.y, posc, ps, hist, repl);
    process_elem(g.z, p.z, posc, ps, hist, repl);
    process_elem(g.w, p.w, posc, ps, hist, repl);
}

__global__ __launch_bounds__(THREADS) void pass1(
    const float* __restrict__ gt, const float* __restrict__ pred,
    unsigned int* __restrict__ counts, unsigned long long* __restrict__ sums,
    unsigned int* __restrict__ posCnt, double* __restrict__ psum,
    int n4, int nTail, long long tailBase)
{
    __shared__ unsigned long long hist[NBINS * REPL];
    for (int i = threadIdx.x; i < NBINS * REPL; i += THREADS) hist[i] = 0ull;
    __syncthreads();

    unsigned int posc = 0;
    float ps = 0.0f;
    const unsigned int repl = threadIdx.x & (REPL - 1);

    const float4* g4p = (const float4*)gt;
    const float4* p4p = (const float4*)pred;
    const int stride = gridDim.x * blockDim.x;
    int i = blockIdx.x * blockDim.x + threadIdx.x;

    // batches of 4 grid-stride iterations: all 8 float4 loads hoisted to the
    // top of the batch. (n4 = 36*stride for the bench shape: 9 full batches.)
    for (; i + 3 * stride < n4; i += 4 * stride) {
        float4 g0 = g4p[i];              float4 p0 = p4p[i];
        float4 g1 = g4p[i + stride];     float4 p1 = p4p[i + stride];
        float4 g2 = g4p[i + 2 * stride]; float4 p2 = p4p[i + 2 * stride];
        float4 g3 = g4p[i + 3 * stride]; float4 p3 = p4p[i + 3 * stride];

        process4(g0, p0, posc, ps, hist, repl);
        process4(g1, p1, posc, ps, hist, repl);
        process4(g2, p2, posc, ps, hist, repl);
        process4(g3, p3, posc, ps, hist, repl);
    }
    for (; i < n4; i += stride) {
        float4 g4 = g4p[i];
        float4 p4 = p4p[i];
        process4(g4, p4, posc, ps, hist, repl);
    }
    if (blockIdx.x == 0 && threadIdx.x < nTail) {
        long long e = tailBase + threadIdx.x;
        process_elem(gt[e], pred[e], posc, ps, hist, repl);
    }

    __syncthreads();
    // flush: fold 4 replicas (packed fields add safely: per-block sum < 2^44,
    // count < 2^20), then one u32 + one u64 global atomic per active bin
    for (int b = threadIdx.x; b < NBINS; b += THREADS) {
        unsigned long long v = hist[(b << 2) | 0] + hist[(b << 2) | 1]
                             + hist[(b << 2) | 2] + hist[(b << 2) | 3];
        if (v) {
            atomicAdd(&counts[b], (unsigned int)(v >> CNTSH));
            atomicAdd(&sums[b],   v & ((1ull << CNTSH) - 1));
        }
    }

    // wave-64 reduce scalars, one atomic per wave
    double pd = (double)ps;
    for (int off = 32; off > 0; off >>= 1) {
        posc += __shfl_down(posc, off);
        pd   += __shfl_down(pd, off);
    }
    if ((threadIdx.x & 63) == 0) {
        if (posc) atomicAdd(posCnt, posc);
        atomicAdd(psum, pd);
    }
}

__global__ __launch_bounds__(256) void finalize(
    const unsigned int* __restrict__ counts,
    const unsigned long long* __restrict__ sums,
    const unsigned int* __restrict__ posCnt, const double* __restrict__ psum,
    float* __restrict__ out)
{
    __shared__ unsigned long long scnt[256];
    __shared__ double             ssum[256];
    __shared__ int                s_chunk;
    __shared__ double             s_topk;

    const int t = threadIdx.x;
    const int BPT = NBINS / 256;          // 8 bins per thread
    const int base = t * BPT;
    const double INVFIX = 1.0 / 1048576.0;

    unsigned long long c = 0; double s = 0.0;
    #pragma unroll
    for (int i = 0; i < BPT; ++i) {
        c += counts[base + i];
        s += (double)sums[base + i] * INVFIX;
    }
    scnt[t] = c; ssum[t] = s;
    if (t == 0) { s_chunk = -1; s_topk = 0.0; }
    __syncthreads();

    // inclusive suffix scan over 256 chunks
    for (int off = 1; off < 256; off <<= 1) {
        unsigned long long cv = (t + off < 256) ? scnt[t + off] : 0ull;
        double             sv = (t + off < 256) ? ssum[t + off] : 0.0;
        __syncthreads();
        scnt[t] += cv; ssum[t] += sv;
        __syncthreads();
    }

    const unsigned int pos = posCnt[0];
    const unsigned long long total = scnt[0];   // exact negative count

    // k = floor(min(max(pos,1)*3.0, neg)) in f32, mirroring reference
    float kf = fminf(fmaxf((float)pos, 1.0f) * 3.0f, (float)total);
    long long k = (long long)floorf(kf);

    unsigned long long Sincl = scnt[t];
    unsigned long long Sexcl = (t < 255) ? scnt[t + 1] : 0ull;
    double SexclSum          = (t < 255) ? ssum[t + 1] : 0.0;

    if (k > 0 && Sexcl < (unsigned long long)k && Sincl >= (unsigned long long)k) {
        double topk = SexclSum;
        unsigned long long need = (unsigned long long)k - Sexcl;
        for (int i = BPT - 1; i >= 0 && need > 0; --i) {
            int b = base + i;
            unsigned long long cb = counts[b];
            if (!cb) continue;
            double sb = (double)sums[b] * INVFIX;
            if (cb <= need) {
                topk += sb;
                need -= cb;
            } else {
                // partial bin: uniform-within-bin model anchored at bin mean
                float lo = __uint_as_float((unsigned)b << 20);
                float hi = (b + 1 < NBINS) ? __uint_as_float((unsigned)(b + 1) << 20) : lo;
                double w = (double)hi - (double)lo;
                double n = (double)cb;
                double r = (double)need;
                double mean = sb / n;
                topk += r * (mean + 0.5 * w * (1.0 - r / n));
                need = 0;
            }
        }
        s_topk = topk;
        s_chunk = t;
    }
    __syncthreads();

    if (t == 0) {
        double topk = (s_chunk >= 0) ? s_topk : 0.0;
        float denf = (float)pos + (float)k;
        denf += 1e-4f;
        double res = (3.0 * (*psum) + topk) / (double)denf;
        out[0] = (float)res;
    }
}

extern "C" void kernel_launch(void* const* d_in, const int* in_sizes, int n_in,
                              void* d_out, int out_size, void* d_ws, size_t ws_size,
                              hipStream_t stream) {
    const float* gt   = (const float*)d_in[0];
    const float* pred = (const float*)d_in[1];
    float* out = (float*)d_out;

    // ws: [0,8) double psum | [8,12) u32 pos | pad | [16,16+8K) u32 counts
    //     | [16+8K, 16+8K+16K) u64 sums
    double*             psum   = (double*)d_ws;
    unsigned int*       posCnt = (unsigned int*)((char*)d_ws + 8);
    unsigned int*       counts = (unsigned int*)((char*)d_ws + 16);
    unsigned long long* sums   = (unsigned long long*)((char*)d_ws + 16 + NBINS * sizeof(unsigned int));

    size_t zbytes = 16 + (size_t)NBINS * (sizeof(unsigned int) + sizeof(unsigned long long));
    hipMemsetAsync(d_ws, 0, zbytes, stream);

    long long n = (long long)in_sizes[0];
    int n4 = (int)(n >> 2);
    int nTail = (int)(n & 3);
    long long tailBase = (long long)n4 * 4;

    pass1<<<dim3(BLOCKS), dim3(THREADS), 0, stream>>>(
        gt, pred, counts, sums, posCnt, psum, n4, nTail, tailBase);
    finalize<<<dim3(1), dim3(256), 0, stream>>>(counts, sums, posCnt, psum, out);
}